// Round 11
// baseline (69.824 us; speedup 1.0000x reference)
//
#include <hip/hip_runtime.h>
#include <stdint.h>

#define TPB 64
#define RCAP 64
#define BAND 0.05f

// d_ws layout (u32 words)
#define WS_BFR   0     // 1280: B fragments [s 5][lane 64][dw 4] (f16, n=2c+dy trick)
#define WS_W1B   1280  // 18:  w1 sign bits [6 c][3 words] (bit k = ic*25+kr*5+kc)
#define WS_W2PK  1298  // 80:  w2 bits [16 oc][5 kr], bit (5c+k)
#define WS_WF1P  1378  // 3000: wf1 bits [120 o][25 pos], bit oc
#define WS_WF2PK 4380  // 336: wf2 bits [84 o][4 q]   (16B-aligned base)
#define WS_WF3PK 4716  // 30:  wf3 bits [10 o][3 q]
#define WS_T2    4746  // 16:  conv2 int thresholds (dmin <= T  <=>  sign+)
#define WS_TF1   4762  // 120: fc1 int thresholds
#define WS_TF2   4882  // 84:  fc2 int thresholds   (end 4966)

typedef _Float16 half8 __attribute__((ext_vector_type(8)));
typedef float f32x4 __attribute__((ext_vector_type(4)));
typedef unsigned int u32x4 __attribute__((ext_vector_type(4)));

__device__ __forceinline__ uint32_t pkf16(float a, float b) {
  uint32_t lo = (uint32_t)__builtin_bit_cast(uint16_t, (_Float16)a);
  uint32_t hi = (uint32_t)__builtin_bit_cast(uint16_t, (_Float16)b);
  return lo | (hi << 16);
}

// lane^1 exchange on the VALU pipe (DPP quad_perm [1,0,3,2]) — not the LDS pipe
__device__ __forceinline__ float qpswap(float v) {
  return __builtin_bit_cast(float, __builtin_amdgcn_mov_dpp(
      __builtin_bit_cast(int, v), 0xB1, 0xF, 0xF, true));
}

// exact fp64 window sum from global x; weights as sign bits b0/b1/b2
__device__ __forceinline__ double win_sum(const float* __restrict__ xb,
                                          uint32_t b0, uint32_t b1, uint32_t b2) {
  double s = 0.0;
#pragma unroll
  for (int ic = 0; ic < 3; ++ic)
#pragma unroll
    for (int rr = 0; rr < 5; ++rr) {
      const float* rp = xb + ic * 1024 + rr * 32;
#pragma unroll
      for (int kc = 0; kc < 5; ++kc) {
        const int idx = ic * 25 + rr * 5 + kc;
        const uint32_t bw = (idx < 32) ? b0 : ((idx < 64) ? b1 : b2);
        double xv = (double)rp[kc];
        s += ((bw >> (idx & 31)) & 1u) ? xv : -xv;
      }
    }
  return s;
}

__global__ __launch_bounds__(256) void prep_kernel(
    const float* __restrict__ w1, const float* __restrict__ w2,
    const float* __restrict__ wf1, const float* __restrict__ wf2,
    const float* __restrict__ wf3,
    const float* __restrict__ b2, const float* __restrict__ bf1,
    const float* __restrict__ bf2, uint32_t* __restrict__ wsu)
{
  int id = blockIdx.x * 256 + threadIdx.x;
  if (id < 1280) {
    // B fragment, dy-in-N: n = 2c+dy (n<12). k-octet o = 4s+g4 -> input row
    // r6 = o/3 (0..5), col-pair cp = o%3. k-slot j2 = dw*2+h ->
    // ic = j2&3, pixel = j2>>2, kc = cp*2+pixel; tap kr = r6-dy must be 0..4.
    int s = id >> 8, r = id & 255, ln = r >> 2, dw = r & 3;
    int g4 = ln >> 4, n = ln & 15;
    int o = 4 * s + g4, r6 = o / 3, cp = o % 3;
    int c = n >> 1, dy = n & 1;
    uint32_t w = 0;
    for (int h = 0; h < 2; ++h) {
      int j2 = dw * 2 + h;
      int ic = j2 & 3, pix = j2 >> 2, kc = cp * 2 + pix, kr = r6 - dy;
      uint32_t f = 0;
      if (n < 12 && o < 18 && ic < 3 && kc < 5 && kr >= 0 && kr <= 4)
        f = (w1[(c * 3 + ic) * 25 + kr * 5 + kc] >= 0.f) ? 0x3C00u : 0xBC00u;
      w |= f << (16 * h);
    }
    wsu[WS_BFR + id] = w;
  } else if (id < 1298) {
    int i = id - 1280, c = i / 3, q = i % 3;
    uint32_t w = 0;
    for (int b = 0; b < 32; ++b) {
      int k = q * 32 + b;
      if (k < 75) w |= (uint32_t)(w1[c*75 + k] >= 0.f) << b;
    }
    wsu[WS_W1B + i] = w;
  } else if (id < 1378) {
    int r = id - 1298, oc = r / 5, kr = r % 5;
    uint32_t w = 0;
    for (int c = 0; c < 6; ++c)
      for (int k = 0; k < 5; ++k)
        w |= (uint32_t)(w2[((oc*6 + c)*5 + kr)*5 + k] >= 0.f) << (5*c + k);
    wsu[WS_W2PK + r] = w;
  } else if (id < 4378) {
    int r = id - 1378, o = r / 25, p = r % 25;
    uint32_t w = 0;
    for (int oc = 0; oc < 16; ++oc)
      w |= (uint32_t)(wf1[o*400 + oc*25 + p] >= 0.f) << oc;
    wsu[WS_WF1P + r] = w;
  } else if (id >= 4380 && id < 4716) {
    int r = id - 4380, o = r / 4, q = r % 4;
    uint32_t w = 0;
    for (int b = 0; b < 32; ++b) {
      int n = q*32 + b;
      if (n < 120) w |= (uint32_t)(wf2[o*120 + n] >= 0.f) << b;
    }
    wsu[WS_WF2PK + r] = w;
  } else if (id >= 4716 && id < 4746) {
    int r = id - 4716, o = r / 3, q = r % 3;
    uint32_t w = 0;
    for (int b = 0; b < 32; ++b) {
      int n = q*32 + b;
      if (n < 84) w |= (uint32_t)(wf3[o*84 + n] >= 0.f) << b;
    }
    wsu[WS_WF3PK + r] = w;
  } else if (id >= WS_T2 && id < WS_T2 + 16) {
    // integer threshold: largest d with (float)(150-2d)+b2 >= 0 (EXACT same fp32 expr)
    int oc = id - WS_T2, T = -1;
    for (int d = 0; d <= 150; ++d)
      if ((float)(150 - 2*d) + b2[oc] >= 0.f) T = d;
    wsu[id] = (uint32_t)T;
  } else if (id >= WS_TF1 && id < WS_TF1 + 120) {
    int o = id - WS_TF1, T = -1;
    for (int d = 0; d <= 400; ++d)
      if ((float)(400 - 2*d) + bf1[o] >= 0.f) T = d;
    wsu[id] = (uint32_t)T;
  } else if (id >= WS_TF2 && id < WS_TF2 + 84) {
    int o = id - WS_TF2, T = -1;
    for (int d = 0; d <= 120; ++d)
      if ((float)(120 - 2*d) + bf2[o] >= 0.f) T = d;
    wsu[id] = (uint32_t)T;
  }
}

// One wave = one block = one image. conv1: 4 independent MFMA chains (2 pooled
// rows x 2 col-groups) for ILP; conv2 in registers + int thresholds; fc LDS-free.
__global__ void __launch_bounds__(TPB, 4) lenet_kernel(
    const float* __restrict__ x,
    const float* __restrict__ b1,
    const float* __restrict__ bf3,
    const uint32_t* __restrict__ wsu,
    float* __restrict__ out)
{
  // Image: [row 32][col 33] pixels of 8B ({f16 c0,c1} {f16 c2,0}); col 32 = zero pad.
  __shared__ __align__(16) uint32_t imgh[2112];   // 8448 B
  __shared__ uint32_t bits1[6][14];               // fully overwritten by conv1
  __shared__ uint32_t border_[6][14];             // fully overwritten by conv1
  __shared__ uint32_t bits2s[25];                 // fully overwritten by conv2
  __shared__ uint32_t rlist[RCAP];
  __shared__ int rcnt;

  const int t = threadIdx.x;                  // lane 0..63
  const int m16 = t & 15;                     // A-row = x position
  const int g4 = t >> 4;                      // k-octet group
  const long long img = blockIdx.x;

  // conv1 B fragments + per-step k-octet offsets (global, L2/L3-resident)
  u32x4 bfr[5];
#pragma unroll
  for (int s = 0; s < 5; ++s)
    bfr[s] = *(const u32x4*)&wsu[WS_BFR + (s << 8) + (t << 2)];
  int koffs[5];
#pragma unroll
  for (int s = 0; s < 5; ++s) {
    const int o = 4 * s + g4;
    koffs[s] = (o < 18) ? (o / 3) * 33 + (o % 3) * 2 : 0;  // o>=18: B=0
  }

  // ---------- load + f16 interleave pack (fully static indexing) ----------
  {
    const int y = t >> 1, xh = t & 1;
    const float* rp = x + img * 3072 + y * 32 + xh * 16;
    const int pixbase = y * 33 + xh * 16;
#pragma unroll
    for (int q = 0; q < 4; ++q) {
      float4 f0 = *(const float4*)(rp +    0 + 4 * q);
      float4 f1 = *(const float4*)(rp + 1024 + 4 * q);
      float4 f2 = *(const float4*)(rp + 2048 + 4 * q);
      uint32_t* d = &imgh[2 * (pixbase + 4 * q)];
      *(uint2*)(d + 0) = make_uint2(pkf16(f0.x, f1.x), pkf16(f2.x, 0.f));
      *(uint2*)(d + 2) = make_uint2(pkf16(f0.y, f1.y), pkf16(f2.y, 0.f));
      *(uint2*)(d + 4) = make_uint2(pkf16(f0.z, f1.z), pkf16(f2.z, 0.f));
      *(uint2*)(d + 6) = make_uint2(pkf16(f0.w, f1.w), pkf16(f2.w, 0.f));
    }
    if (t < 32)  // zero pad col 32 of every row
      *(uint2*)&imgh[2 * (t * 33 + 32)] = make_uint2(0u, 0u);
    if (t == 0) rcnt = 0;
  }
  __syncthreads();

  // ---------- conv1: f16 MFMA dy-in-N; 2 pooled rows x 2 xg = 4 chains/iter ----------
  {
    const int n = m16;
    const int c = n >> 1;
    const float bcr = b1[(n < 12) ? c : 0];   // per-lane global (L3)

    auto epilogue = [&](f32x4 aX, f32x4 aY, int pyi) {
      // x-pair pool in-lane (rows g4*4+q); dy-pair pool via DPP lane^1 (VALU pipe)
      float pX0 = fmaxf(aX[0], aX[1]), pX1 = fmaxf(aX[2], aX[3]);
      float pY0 = fmaxf(aY[0], aY[1]), pY1 = fmaxf(aY[2], aY[3]);
      float qX0 = fmaxf(pX0, qpswap(pX0));
      float qX1 = fmaxf(pX1, qpswap(pX1));
      float qY0 = fmaxf(pY0, qpswap(pY0));
      float qY1 = fmaxf(pY1, qpswap(pY1));
      uint32_t comb = 0;
      {
        float v0 = qX0 + bcr, v1 = qX1 + bcr, v2 = qY0 + bcr, v3 = qY1 + bcr;
        const int p0 = g4 * 2, p1 = g4 * 2 + 1, p2 = 6 + g4 * 2, p3 = 7 + g4 * 2;
        if (fabsf(v0) < BAND) comb |= 1u << (16 + p0); else if (v0 >= 0.f) comb |= 1u << p0;
        if (fabsf(v1) < BAND) comb |= 1u << (16 + p1); else if (v1 >= 0.f) comb |= 1u << p1;
        if (fabsf(v2) < BAND) comb |= 1u << (16 + p2); else if (v2 >= 0.f) comb |= 1u << p2;
        if (fabsf(v3) < BAND) comb |= 1u << (16 + p3); else if (v3 >= 0.f) comb |= 1u << p3;
      }
      comb |= __shfl_xor(comb, 16);
      comb |= __shfl_xor(comb, 32);
      if (g4 == 0 && n < 12 && (n & 1) == 0) {
        bits1[c][pyi]   = comb & 0x3FFFu;
        border_[c][pyi] = comb >> 16;
      }
    };

    for (int p = 0; p < 7; ++p) {
      const int rpA = (2 * p) * 33 + m16;           // pyi = p
      const int rpB = (2 * (p + 7)) * 33 + m16;     // pyi = p + 7
      f32x4 aX0 = {0.f,0.f,0.f,0.f}, aY0 = {0.f,0.f,0.f,0.f};
      f32x4 aX1 = {0.f,0.f,0.f,0.f}, aY1 = {0.f,0.f,0.f,0.f};
#pragma unroll
      for (int s = 0; s < 5; ++s) {
        const uint2* pX0 = (const uint2*)&imgh[2 * (rpA + koffs[s])];
        const uint2* pY0 = (const uint2*)&imgh[2 * (rpA + 12 + koffs[s])];
        const uint2* pX1 = (const uint2*)&imgh[2 * (rpB + koffs[s])];
        const uint2* pY1 = (const uint2*)&imgh[2 * (rpB + 12 + koffs[s])];
        uint2 a0 = pX0[0], a1 = pX0[1];
        uint2 b0 = pY0[0], b1_ = pY0[1];
        uint2 c0 = pX1[0], c1 = pX1[1];
        uint2 d0 = pY1[0], d1 = pY1[1];
        u32x4 wa = {a0.x, a0.y, a1.x, a1.y};
        u32x4 wb = {b0.x, b0.y, b1_.x, b1_.y};
        u32x4 wc = {c0.x, c0.y, c1.x, c1.y};
        u32x4 wd = {d0.x, d0.y, d1.x, d1.y};
        aX0 = __builtin_amdgcn_mfma_f32_16x16x32_f16(
                __builtin_bit_cast(half8, wa), __builtin_bit_cast(half8, bfr[s]), aX0, 0, 0, 0);
        aY0 = __builtin_amdgcn_mfma_f32_16x16x32_f16(
                __builtin_bit_cast(half8, wb), __builtin_bit_cast(half8, bfr[s]), aY0, 0, 0, 0);
        aX1 = __builtin_amdgcn_mfma_f32_16x16x32_f16(
                __builtin_bit_cast(half8, wc), __builtin_bit_cast(half8, bfr[s]), aX1, 0, 0, 0);
        aY1 = __builtin_amdgcn_mfma_f32_16x16x32_f16(
                __builtin_bit_cast(half8, wd), __builtin_bit_cast(half8, bfr[s]), aY1, 0, 0, 0);
      }
      epilogue(aX0, aY0, p);
      epilogue(aX1, aY1, p + 7);
    }
  }
  __syncthreads();

  // ---------- borderline list build ----------
  for (int id = t; id < 84; id += TPB) {
    uint32_t bw = ((uint32_t*)border_)[id];
    while (bw) {
      int pj = __ffs(bw) - 1;
      bw &= bw - 1;
      int slot = atomicAdd(&rcnt, 1);
      if (slot < RCAP) rlist[slot] = (uint32_t)(id * 16 + pj);
    }
  }
  __syncthreads();

  // ---------- exact fp64 resolve from global (one window per lane; cold) ----------
  {
    const int cnt = min(rcnt, RCAP);
    for (int k = t; k < cnt * 4; k += TPB) {
      const int e = k >> 2, win = k & 3;
      const uint32_t ent = rlist[e];
      const int pj = ent & 15, w = ent >> 4;
      const int pi = w % 14, c = w / 14;
      const int dr = win >> 1, dc = win & 1;
      const float* xb = x + img * 3072 + (2*pi + dr) * 32 + (2*pj + dc);
      double s = win_sum(xb, wsu[WS_W1B + c*3], wsu[WS_W1B + c*3+1], wsu[WS_W1B + c*3+2]);
      double s1 = fmax(s, __shfl_xor(s, 1));
      double sm = fmax(s1, __shfl_xor(s1, 2));
      if (win == 0) {
        if (sm + (double)b1[c] >= 0.0)
          atomicOr(&((uint32_t*)bits1)[w], 1u << pj);
      }
    }
    if (rcnt > RCAP) {  // fallback (never in practice): rescan all masks
      for (int id = t; id < 1176; id += TPB) {
        const int w = id / 14, pj = id % 14;
        if ((((uint32_t*)border_)[w] >> pj) & 1u) {
          const int pi = w % 14, c = w / 14;
          double best = -1e300;
          for (int dr = 0; dr < 2; ++dr)
            for (int dc = 0; dc < 2; ++dc) {
              const float* xb = x + img * 3072 + (2*pi + dr) * 32 + (2*pj + dc);
              double s = win_sum(xb, wsu[WS_W1B + c*3], wsu[WS_W1B + c*3+1], wsu[WS_W1B + c*3+2]);
              best = best > s ? best : s;
            }
          if (best + (double)b1[c] >= 0.0)
            atomicOr(&((uint32_t*)bits1)[w], 1u << pj);
        }
      }
    }
  }
  __syncthreads();

  // ---------- conv2: register ppatch + scalar w2 + int thresholds ----------
  {
    const int la  = (t < 50) ? t : 49;      // lanes 50-63 mirror lane 49 (discarded)
    const int i   = la / 5;                 // unpooled row 0..9
    const int pjc = la % 5;                 // pooled col
    const int j0  = 2 * pjc;
    uint32_t ppA[5], ppB[5];
#pragma unroll
    for (int kr = 0; kr < 5; ++kr) {
      uint32_t wa = 0, wb = 0;
#pragma unroll
      for (int c = 0; c < 6; ++c) {
        uint32_t bc = bits1[c][i + kr];     // broadcast-clean b32 reads
        wa |= ((bc >> j0) & 31u) << (5*c);
        wb |= ((bc >> (j0 + 1)) & 31u) << (5*c);
      }
      ppA[kr] = wa; ppB[kr] = wb;
    }
    const int partner = (i & 1) ? (la - 5) : (la + 5);
    uint32_t myword = 0;
#pragma unroll 4
    for (int oc = 0; oc < 16; ++oc) {
      int dA = 0, dB = 0;
#pragma unroll
      for (int kr = 0; kr < 5; ++kr) {
        const uint32_t wv = wsu[WS_W2PK + oc*5 + kr];   // uniform -> s_load
        dA += __popc(ppA[kr] ^ wv);
        dB += __popc(ppB[kr] ^ wv);
      }
      int dm = min(dA, dB);
      int dp = __shfl(dm, partner);
      int dmin = min(dm, dp);
      myword |= (dmin <= (int)wsu[WS_T2 + oc] ? 1u : 0u) << oc;  // uniform threshold
    }
    if (t < 50 && (i & 1) == 0) bits2s[(i >> 1) * 5 + pjc] = myword;
  }
  __syncthreads();

  // ---------- fc1: bits2 broadcast to regs, wf1 rows from global, ballot out ----------
  uint32_t f1w0, f1w1, f1w2, f1w3;
  {
    uint32_t p2[25];
#pragma unroll
    for (int p = 0; p < 25; ++p) p2[p] = bits2s[p];
    const uint32_t* wrA = wsu + WS_WF1P + t * 25;
    int d1 = 0;
#pragma unroll
    for (int p = 0; p < 25; ++p) d1 += __popc(p2[p] ^ wrA[p]);
    const bool act2 = (t < 56);
    const int o2 = 64 + t;
    int d2 = 0;
    const uint32_t* wrB = wsu + WS_WF1P + o2 * 25;
    if (act2) {
#pragma unroll
      for (int p = 0; p < 25; ++p) d2 += __popc(p2[p] ^ wrB[p]);
    }
    unsigned long long mA = __ballot(d1 <= (int)wsu[WS_TF1 + t]);
    unsigned long long mB = __ballot(act2 && (d2 <= (int)wsu[WS_TF1 + (act2 ? o2 : 0)]));
    f1w0 = (uint32_t)mA; f1w1 = (uint32_t)(mA >> 32);
    f1w2 = (uint32_t)mB; f1w3 = (uint32_t)(mB >> 32);
  }

  // ---------- fc2: wave-uniform activations, per-lane wf2 rows, ballot out ----------
  uint32_t f2w0, f2w1, f2w2;
  {
    const uint32_t* wr = wsu + WS_WF2PK + t * 4;
    int d3 = __popc(f1w0 ^ wr[0]) + __popc(f1w1 ^ wr[1]) +
             __popc(f1w2 ^ wr[2]) + __popc(f1w3 ^ wr[3]);
    const bool act4 = (t < 20);
    const int o4 = 64 + t;
    const uint32_t* wr2 = wsu + WS_WF2PK + (act4 ? o4 : 0) * 4;
    int d4 = 0;
    if (act4)
      d4 = __popc(f1w0 ^ wr2[0]) + __popc(f1w1 ^ wr2[1]) +
           __popc(f1w2 ^ wr2[2]) + __popc(f1w3 ^ wr2[3]);
    unsigned long long mC = __ballot((t < 84) && (d3 <= (int)wsu[WS_TF2 + ((t < 84) ? t : 0)]));
    unsigned long long mD = __ballot(act4 && (d4 <= (int)wsu[WS_TF2 + (act4 ? o4 : 0)]));
    f2w0 = (uint32_t)mC; f2w1 = (uint32_t)(mC >> 32); f2w2 = (uint32_t)mD;
  }

  // ---------- fc3 ----------
  if (t < 10) {
    int d = __popc(f2w0 ^ wsu[WS_WF3PK + t*3 + 0]) +
            __popc(f2w1 ^ wsu[WS_WF3PK + t*3 + 1]) +
            __popc(f2w2 ^ wsu[WS_WF3PK + t*3 + 2]);
    out[img*10 + t] = (float)(84 - 2*d) + bf3[t];
  }
}

extern "C" void kernel_launch(void* const* d_in, const int* in_sizes, int n_in,
                              void* d_out, int out_size, void* d_ws, size_t ws_size,
                              hipStream_t stream)
{
  const float* x   = (const float*)d_in[0];
  const float* w1  = (const float*)d_in[1];
  const float* b1  = (const float*)d_in[2];
  const float* w2  = (const float*)d_in[3];
  const float* b2  = (const float*)d_in[4];
  const float* wf1 = (const float*)d_in[5];
  const float* bf1 = (const float*)d_in[6];
  const float* wf2 = (const float*)d_in[7];
  const float* bf2 = (const float*)d_in[8];
  const float* wf3 = (const float*)d_in[9];
  const float* bf3 = (const float*)d_in[10];
  uint32_t* wsu = (uint32_t*)d_ws;

  const int imgs = in_sizes[0] / 3072;
  hipLaunchKernelGGL(prep_kernel, dim3(20), dim3(256), 0, stream,
                     w1, w2, wf1, wf2, wf3, b2, bf1, bf2, wsu);
  hipLaunchKernelGGL(lenet_kernel, dim3(imgs), dim3(TPB), 0, stream,
                     x, b1, bf3, wsu, (float*)d_out);
}